// Round 8
// baseline (462.685 us; speedup 1.0000x reference)
//
#include <hip/hip_runtime.h>

// SNN, bit-exact replication of a numpy float32 forward:
//   - matmuls: sequential-k FMA chain (BLAS sgemm microkernel order), bias added after
//   - elementwise recurrence: separately-rounded mul/add/sub (no fp contraction)
// B=4096, T=128, D_in=H=64, D_out=16. One wave per batch element, lane = hidden unit.
// out = concat(readout_spk [B,16], spk2 [B,T,64]) as f32.

#define T_STEPS 128
#define D_IN    64
#define H_DIM   64
#define D_OUT   16

__global__ __launch_bounds__(64) void snn_exact_f32(
    const float* __restrict__ x,    // [B, T, D_in]
    const float* __restrict__ W1,   // [H, D_in]
    const float* __restrict__ b1,   // [H]
    const float* __restrict__ W2,   // [H, H]
    const float* __restrict__ b2,   // [H]
    const float* __restrict__ Wr,   // [D_out, H]
    const float* __restrict__ br,   // [D_out]
    float* __restrict__ out_read,   // [B, D_out]
    float* __restrict__ out_spk)    // [B, T, H]
{
    const int b    = blockIdx.x;
    const int lane = threadIdx.x;

    // weight rows in registers (scalarized)
    float w1[D_IN], w2[H_DIM];
    {
        const float4* p = reinterpret_cast<const float4*>(W1 + lane * D_IN);
#pragma unroll
        for (int i = 0; i < 16; ++i) {
            float4 v = p[i];
            w1[4*i] = v.x; w1[4*i+1] = v.y; w1[4*i+2] = v.z; w1[4*i+3] = v.w;
        }
    }
    {
        const float4* p = reinterpret_cast<const float4*>(W2 + lane * H_DIM);
#pragma unroll
        for (int i = 0; i < 16; ++i) {
            float4 v = p[i];
            w2[4*i] = v.x; w2[4*i+1] = v.y; w2[4*i+2] = v.z; w2[4*i+3] = v.w;
        }
    }
    const float b1v = b1[lane];
    const float b2v = b2[lane];

    __shared__ __align__(16) float xs[2][D_IN];
    const float* xb = x + (size_t)b * T_STEPS * D_IN;
    float xg = xb[lane];            // prefetch t=0

    float mem1 = 0.f, mem2 = 0.f, spksum = 0.f;
    float* spk_b = out_spk + (size_t)b * T_STEPS * H_DIM;

    for (int t = 0; t < T_STEPS; ++t) {
        xs[t & 1][lane] = xg;
        if (t + 1 < T_STEPS) xg = xb[(t + 1) * D_IN + lane];
        __syncthreads();

        // x_t into registers (vector LDS loads; load order irrelevant)
        float xr[D_IN];
        {
            const float4* xv = reinterpret_cast<const float4*>(xs[t & 1]);
#pragma unroll
            for (int i = 0; i < 16; ++i) {
                float4 v = xv[i];
                xr[4*i] = v.x; xr[4*i+1] = v.y; xr[4*i+2] = v.z; xr[4*i+3] = v.w;
            }
        }

        // ---- layer 1: sequential-k FMA chain == sgemm order; bias rounded after
        float c1 = 0.f;
#pragma unroll
        for (int k = 0; k < D_IN; ++k) c1 = fmaf(xr[k], w1[k], c1);
        float cur1 = __fadd_rn(c1, b1v);

        // mem1 = ((0.9f*mem1) + cur1) - reset1, each op separately rounded
        float r1 = (mem1 > 1.0f) ? 1.0f : 0.0f;     // reset from PREVIOUS mem1
        mem1 = __fsub_rn(__fadd_rn(__fmul_rn(0.9f, mem1), cur1), r1);

        // ---- layer 2: binary spikes; fma(spk,w,c) == (spk ? round(c+w) : c)
        unsigned long long msk = __ballot(mem1 > 1.0f);
        float c2 = 0.f;
#pragma unroll
        for (int j = 0; j < H_DIM; ++j) {
            float sel = ((msk >> j) & 1ull) ? 1.0f : 0.0f;
            c2 = fmaf(sel, w2[j], c2);              // sequential-j chain
        }
        float cur2 = __fadd_rn(c2, b2v);

        float r2 = (mem2 > 1.0f) ? 1.0f : 0.0f;     // reset from PREVIOUS mem2
        mem2 = __fsub_rn(__fadd_rn(__fmul_rn(0.9f, mem2), cur2), r2);

        float s2 = (mem2 > 1.0f) ? 1.0f : 0.0f;
        spksum = __fadd_rn(spksum, s2);             // integer-valued: exact
        spk_b[t * H_DIM + lane] = s2;               // coalesced 256B store
    }

    // ---- readout: mean is integer/128 (exact); sequential-j fma + bias after
    __shared__ float avg[H_DIM];
    avg[lane] = spksum * 0.0078125f;                // exact
    __syncthreads();
    if (lane < D_OUT) {
        const float* wr = Wr + lane * H_DIM;
        float acc = 0.f;
#pragma unroll
        for (int j = 0; j < H_DIM; ++j) acc = fmaf(avg[j], wr[j], acc);
        out_read[(size_t)b * D_OUT + lane] = __fadd_rn(acc, br[lane]);
    }
}

extern "C" void kernel_launch(void* const* d_in, const int* in_sizes, int n_in,
                              void* d_out, int out_size, void* d_ws, size_t ws_size,
                              hipStream_t stream) {
    const float* x  = (const float*)d_in[0];
    const float* W1 = (const float*)d_in[1];
    const float* b1 = (const float*)d_in[2];
    const float* W2 = (const float*)d_in[3];
    const float* b2 = (const float*)d_in[4];
    const float* Wr = (const float*)d_in[5];
    const float* br = (const float*)d_in[6];

    const int B = in_sizes[0] / (T_STEPS * D_IN);   // 4096

    float* out      = (float*)d_out;
    float* out_read = out;                          // [B, 16]
    float* out_spk  = out + (size_t)B * D_OUT;      // [B, T, H]

    snn_exact_f32<<<B, 64, 0, stream>>>(x, W1, b1, W2, b2, Wr, br,
                                        out_read, out_spk);
}

// Round 9
// 458.166 us; speedup vs baseline: 1.0099x; 1.0099x over previous
//
#include <hip/hip_runtime.h>

// SNN, bit-exact numpy f32 semantics (sequential-k FMA chains, separately-rounded
// elementwise ops). Round 9: 4 waves/block, per-wave LDS slices, ZERO barriers.
// B=4096, T=128, D_in=H=64, D_out=16. One wave per batch element, lane = hidden unit.

#define T_STEPS 128
#define D_IN    64
#define H_DIM   64
#define D_OUT   16
#define WPB     4      // waves per 256-thread block

__global__ __launch_bounds__(256) void snn_exact_f32_w4(
    const float* __restrict__ x,    // [B, T, D_in]
    const float* __restrict__ W1,   // [H, D_in]
    const float* __restrict__ b1,   // [H]
    const float* __restrict__ W2,   // [H, H]
    const float* __restrict__ b2,   // [H]
    const float* __restrict__ Wr,   // [D_out, H]
    const float* __restrict__ br,   // [D_out]
    float* __restrict__ out_read,   // [B, D_out]
    float* __restrict__ out_spk)    // [B, T, H]
{
    const int wave = threadIdx.x >> 6;
    const int lane = threadIdx.x & 63;
    const int b    = blockIdx.x * WPB + wave;

    // weight rows in registers (lane = hidden unit; same for every wave)
    float w1[D_IN], w2[H_DIM];
    {
        const float4* p = reinterpret_cast<const float4*>(W1 + lane * D_IN);
#pragma unroll
        for (int i = 0; i < 16; ++i) {
            float4 v = p[i];
            w1[4*i] = v.x; w1[4*i+1] = v.y; w1[4*i+2] = v.z; w1[4*i+3] = v.w;
        }
    }
    {
        const float4* p = reinterpret_cast<const float4*>(W2 + lane * H_DIM);
#pragma unroll
        for (int i = 0; i < 16; ++i) {
            float4 v = p[i];
            w2[4*i] = v.x; w2[4*i+1] = v.y; w2[4*i+2] = v.z; w2[4*i+3] = v.w;
        }
    }
    const float b1v = b1[lane];
    const float b2v = b2[lane];

    // per-wave LDS slices -> wave-synchronous, no __syncthreads anywhere
    __shared__ __align__(16) float xs[WPB][2][D_IN];
    __shared__ float avgs[WPB][H_DIM];

    const float* xb = x + (size_t)b * T_STEPS * D_IN;
    float xg = xb[lane];            // prefetch t=0

    float mem1 = 0.f, mem2 = 0.f, spksum = 0.f;
    float* spk_b = out_spk + (size_t)b * T_STEPS * H_DIM;

    for (int t = 0; t < T_STEPS; ++t) {
        xs[wave][t & 1][lane] = xg;
        if (t + 1 < T_STEPS) xg = xb[(t + 1) * D_IN + lane];

        // x_t into registers (vector LDS loads; wave-coherent, compiler waits lgkmcnt)
        float xr[D_IN];
        {
            const float4* xv = reinterpret_cast<const float4*>(xs[wave][t & 1]);
#pragma unroll
            for (int i = 0; i < 16; ++i) {
                float4 v = xv[i];
                xr[4*i] = v.x; xr[4*i+1] = v.y; xr[4*i+2] = v.z; xr[4*i+3] = v.w;
            }
        }

        // ---- layer 1: sequential-k FMA chain (sgemm order); bias rounded after
        float c1 = 0.f;
#pragma unroll
        for (int k = 0; k < D_IN; ++k) c1 = fmaf(xr[k], w1[k], c1);
        float cur1 = __fadd_rn(c1, b1v);

        // mem1 = ((0.9f*mem1) + cur1) - reset1, each op separately rounded
        float r1 = (mem1 > 1.0f) ? 1.0f : 0.0f;     // reset from PREVIOUS mem1
        mem1 = __fsub_rn(__fadd_rn(__fmul_rn(0.9f, mem1), cur1), r1);

        // ---- layer 2: wave-level ballot (64-bit, per-wave); sequential-j chain
        unsigned long long msk = __ballot(mem1 > 1.0f);
        float c2 = 0.f;
#pragma unroll
        for (int j = 0; j < H_DIM; ++j) {
            float sel = ((msk >> j) & 1ull) ? 1.0f : 0.0f;
            c2 = fmaf(sel, w2[j], c2);
        }
        float cur2 = __fadd_rn(c2, b2v);

        float r2 = (mem2 > 1.0f) ? 1.0f : 0.0f;     // reset from PREVIOUS mem2
        mem2 = __fsub_rn(__fadd_rn(__fmul_rn(0.9f, mem2), cur2), r2);

        float s2 = (mem2 > 1.0f) ? 1.0f : 0.0f;
        spksum = __fadd_rn(spksum, s2);             // integer-valued: exact
        spk_b[t * H_DIM + lane] = s2;               // coalesced 256B store/wave
    }

    // ---- readout: mean = integer/128 (exact); sequential-j fma + bias after
    avgs[wave][lane] = spksum * 0.0078125f;
    if (lane < D_OUT) {
        const float* wr = Wr + lane * H_DIM;
        float acc = 0.f;
#pragma unroll
        for (int j = 0; j < H_DIM; ++j) acc = fmaf(avgs[wave][j], wr[j], acc);
        out_read[(size_t)b * D_OUT + lane] = __fadd_rn(acc, br[lane]);
    }
}

extern "C" void kernel_launch(void* const* d_in, const int* in_sizes, int n_in,
                              void* d_out, int out_size, void* d_ws, size_t ws_size,
                              hipStream_t stream) {
    const float* x  = (const float*)d_in[0];
    const float* W1 = (const float*)d_in[1];
    const float* b1 = (const float*)d_in[2];
    const float* W2 = (const float*)d_in[3];
    const float* b2 = (const float*)d_in[4];
    const float* Wr = (const float*)d_in[5];
    const float* br = (const float*)d_in[6];

    const int B = in_sizes[0] / (T_STEPS * D_IN);   // 4096

    float* out      = (float*)d_out;
    float* out_read = out;                          // [B, 16]
    float* out_spk  = out + (size_t)B * D_OUT;      // [B, T, H]

    snn_exact_f32_w4<<<B / WPB, 256, 0, stream>>>(x, W1, b1, W2, b2, Wr, br,
                                                  out_read, out_spk);
}

// Round 10
// 448.610 us; speedup vs baseline: 1.0314x; 1.0213x over previous
//
#include <hip/hip_runtime.h>

// SNN, bit-exact numpy f32 semantics (sequential-k single-accumulator FMA chains,
// separately-rounded elementwise ops). Round 10: software-pipelined — layer-1 dot
// for step t+1 interleaves with layer-2 chain of step t (two independent dependent
// chains -> 2x ILP per wave, hides FMA latency at ~2 waves/SIMD).
// B=4096, T=128, D_in=H=64, D_out=16. One wave per batch row, lane = hidden unit.

#define T_STEPS 128
#define D_IN    64
#define H_DIM   64
#define D_OUT   16
#define WPB     4      // waves per 256-thread block

__global__ __launch_bounds__(256) void snn_exact_f32_pipe(
    const float* __restrict__ x,    // [B, T, D_in]
    const float* __restrict__ W1,   // [H, D_in]
    const float* __restrict__ b1,   // [H]
    const float* __restrict__ W2,   // [H, H]
    const float* __restrict__ b2,   // [H]
    const float* __restrict__ Wr,   // [D_out, H]
    const float* __restrict__ br,   // [D_out]
    float* __restrict__ out_read,   // [B, D_out]
    float* __restrict__ out_spk)    // [B, T, H]
{
    const int wave = threadIdx.x >> 6;
    const int lane = threadIdx.x & 63;
    const int b    = blockIdx.x * WPB + wave;

    // weight rows in registers (lane = hidden unit)
    float w1[D_IN], w2[H_DIM];
    {
        const float4* p = reinterpret_cast<const float4*>(W1 + lane * D_IN);
#pragma unroll
        for (int i = 0; i < 16; ++i) {
            float4 v = p[i];
            w1[4*i] = v.x; w1[4*i+1] = v.y; w1[4*i+2] = v.z; w1[4*i+3] = v.w;
        }
    }
    {
        const float4* p = reinterpret_cast<const float4*>(W2 + lane * H_DIM);
#pragma unroll
        for (int i = 0; i < 16; ++i) {
            float4 v = p[i];
            w2[4*i] = v.x; w2[4*i+1] = v.y; w2[4*i+2] = v.z; w2[4*i+3] = v.w;
        }
    }
    const float b1v = b1[lane];
    const float b2v = b2[lane];

    // per-wave LDS slices -> wave-synchronous, no __syncthreads in the loop
    __shared__ __align__(16) float xs[WPB][2][D_IN];
    __shared__ float avgs[WPB][H_DIM];

    const float* xb = x + (size_t)b * T_STEPS * D_IN;

    // ---- prologue: stage x_0, compute c1 for t=0, prefetch x_1 ----
    float xg = xb[lane];                 // x_0
    xs[wave][0][lane] = xg;
    xg = xb[D_IN + lane];                // x_1
    float c1 = 0.f;
    {
        const float4* xv = reinterpret_cast<const float4*>(xs[wave][0]);
#pragma unroll
        for (int i = 0; i < 16; ++i) {
            float4 v = xv[i];
            c1 = fmaf(v.x, w1[4*i],   c1);
            c1 = fmaf(v.y, w1[4*i+1], c1);
            c1 = fmaf(v.z, w1[4*i+2], c1);
            c1 = fmaf(v.w, w1[4*i+3], c1);
        }
    }

    float mem1 = 0.f, mem2 = 0.f, spksum = 0.f;
    float* spk_b = out_spk + (size_t)b * T_STEPS * H_DIM;

    for (int t = 0; t < T_STEPS; ++t) {
        const int nxt = (t & 1) ^ 1;

        // stage x_{t+1} (held in xg) into the other LDS buffer; prefetch x_{t+2}
        xs[wave][nxt][lane] = xg;
        {
            const int tn = (t + 2 < T_STEPS) ? (t + 2) : (T_STEPS - 1);
            xg = xb[tn * D_IN + lane];   // clamped: redundant-safe at the tail
        }

        // ---- step t, layer 1 result is ready in c1 ----
        float cur1 = __fadd_rn(c1, b1v);
        float r1 = (mem1 > 1.0f) ? 1.0f : 0.0f;     // reset from PREVIOUS mem1
        mem1 = __fsub_rn(__fadd_rn(__fmul_rn(0.9f, mem1), cur1), r1);

        unsigned long long msk = __ballot(mem1 > 1.0f);

        // ---- interleaved independent chains:
        //      c2  = layer-2 chain for step t (sequential j)
        //      c1n = layer-1 chain for step t+1 (sequential k)
        float c2 = 0.f, c1n = 0.f;
        const float4* xv = reinterpret_cast<const float4*>(xs[wave][nxt]);
#pragma unroll
        for (int i = 0; i < 16; ++i) {
            float4 v = xv[i];
            float s0 = ((msk >> (4*i+0)) & 1ull) ? 1.0f : 0.0f;
            float s1 = ((msk >> (4*i+1)) & 1ull) ? 1.0f : 0.0f;
            float s2 = ((msk >> (4*i+2)) & 1ull) ? 1.0f : 0.0f;
            float s3 = ((msk >> (4*i+3)) & 1ull) ? 1.0f : 0.0f;
            c1n = fmaf(v.x, w1[4*i],   c1n);
            c2  = fmaf(s0,  w2[4*i],   c2);
            c1n = fmaf(v.y, w1[4*i+1], c1n);
            c2  = fmaf(s1,  w2[4*i+1], c2);
            c1n = fmaf(v.z, w1[4*i+2], c1n);
            c2  = fmaf(s2,  w2[4*i+2], c2);
            c1n = fmaf(v.w, w1[4*i+3], c1n);
            c2  = fmaf(s3,  w2[4*i+3], c2);
        }
        c1 = c1n;                       // dot for step t+1 (discarded after t=127)

        float cur2 = __fadd_rn(c2, b2v);
        float r2 = (mem2 > 1.0f) ? 1.0f : 0.0f;     // reset from PREVIOUS mem2
        mem2 = __fsub_rn(__fadd_rn(__fmul_rn(0.9f, mem2), cur2), r2);

        float s2v = (mem2 > 1.0f) ? 1.0f : 0.0f;
        spksum = __fadd_rn(spksum, s2v);            // integer-valued: exact
        spk_b[t * H_DIM + lane] = s2v;              // coalesced 256B store/wave
    }

    // ---- readout: mean = integer/128 (exact); sequential-j fma + bias after
    avgs[wave][lane] = spksum * 0.0078125f;
    if (lane < D_OUT) {
        const float* wr = Wr + lane * H_DIM;
        float acc = 0.f;
#pragma unroll
        for (int j = 0; j < H_DIM; ++j) acc = fmaf(avgs[wave][j], wr[j], acc);
        out_read[(size_t)b * D_OUT + lane] = __fadd_rn(acc, br[lane]);
    }
}

extern "C" void kernel_launch(void* const* d_in, const int* in_sizes, int n_in,
                              void* d_out, int out_size, void* d_ws, size_t ws_size,
                              hipStream_t stream) {
    const float* x  = (const float*)d_in[0];
    const float* W1 = (const float*)d_in[1];
    const float* b1 = (const float*)d_in[2];
    const float* W2 = (const float*)d_in[3];
    const float* b2 = (const float*)d_in[4];
    const float* Wr = (const float*)d_in[5];
    const float* br = (const float*)d_in[6];

    const int B = in_sizes[0] / (T_STEPS * D_IN);   // 4096

    float* out      = (float*)d_out;
    float* out_read = out;                          // [B, 16]
    float* out_spk  = out + (size_t)B * D_OUT;      // [B, T, H]

    snn_exact_f32_pipe<<<B / WPB, 256, 0, stream>>>(x, W1, b1, W2, b2, Wr, br,
                                                    out_read, out_spk);
}